// Round 9
// baseline (814.716 us; speedup 1.0000x reference)
//
#include <hip/hip_runtime.h>
#include <hip/hip_cooperative_groups.h>

namespace cg = cooperative_groups;

#define NN 50000
#define NE 800000
#define KD 256
#define CD 128
#define NB 196            // scan blocks: 196*256 = 50176 >= NN
#define GEMM_BLOCKS 782   // (NN+63)/64
#define GRID 1024
#define HIST_BLOCKS (GRID - GEMM_BLOCKS)   // 242

typedef __attribute__((ext_vector_type(8))) short short8;
typedef __attribute__((ext_vector_type(4))) float floatx4;

__device__ inline unsigned short f2bf(float f) {
    unsigned u = __float_as_uint(f);
    unsigned r = (u + 0x7FFFu + ((u >> 16) & 1u)) >> 16;   // RNE
    return (unsigned short)r;
}
__device__ inline float bf2f_lo(unsigned u) { return __uint_as_float(u << 16); }
__device__ inline float bf2f_hi(unsigned u) { return __uint_as_float(u & 0xFFFF0000u); }

// ===================== single cooperative mega-kernel =====================
// phase 0: zero histogram + W fp32->bf16 transpose
// phase 1: GEMM (blocks <782) || degree histogram+rank (blocks >=782)
// phase 2: 2-step scan -> start[], dinv[]
// phase 3: meta_write (atomic-free CSR placement)
// phase 4: pull aggregation + fused epilogue
__global__ __launch_bounds__(256, 4) void mega(
        const float* __restrict__ x, const float* __restrict__ Wm,
        const int* __restrict__ col, const float* __restrict__ ew,
        const int* __restrict__ row,
        const float* __restrict__ bias, const float* __restrict__ alpha,
        float* __restrict__ out,
        unsigned long long* __restrict__ packed,
        int* __restrict__ start, int* __restrict__ local,
        int* __restrict__ partials, float* __restrict__ dinv,
        unsigned short* __restrict__ rank, unsigned* __restrict__ meta,
        unsigned short* __restrict__ Wt, unsigned short* __restrict__ hb) {
    cg::grid_group grid = cg::this_grid();
    __shared__ unsigned short As[64][40];
    __shared__ unsigned short Bs[128][40];

    const int tid = threadIdx.x;
    const int b   = blockIdx.x;

    // ---------------- phase 0: zero packed (blocks 32..) + W transpose (blocks 0..31)
    if (b < 32) {
        unsigned short (*t)[33] = (unsigned short (*)[33])&As[0][0];  // 2112 B scratch
        const int bk = (b >> 2) * 32;
        const int bn = (b & 3) * 32;
        const int tx = tid & 31;
        const int ty = tid >> 5;
#pragma unroll
        for (int i = 0; i < 32; i += 8)
            t[ty + i][tx] = f2bf(Wm[(size_t)(bk + ty + i) * CD + bn + tx]);
        __syncthreads();
#pragma unroll
        for (int i = 0; i < 32; i += 8)
            Wt[(size_t)(bn + ty + i) * KD + bk + tx] = t[tx][ty + i];
    } else {
        int idx = (b - 32) * 256 + tid;   // (1024-32)*256 = 253952 >= NN
        if (idx < NN) packed[idx] = 0;
    }
    grid.sync();

    // ---------------- phase 1: GEMM || histogram
    if (b < GEMM_BLOCKS) {
        const int wave = tid >> 6;
        const int lane = tid & 63;
        const int row0 = b * 64;
        const int m0   = wave * 16;
        const int lr   = lane & 15;
        const int quad = lane >> 4;
        const int ar = tid >> 2;
        const int aq = tid & 3;
        const int bn = tid >> 1;
        const int bh = (tid & 1) * 16;

        floatx4 acc[8];
#pragma unroll
        for (int nt = 0; nt < 8; nt++) acc[nt] = (floatx4){0.f, 0.f, 0.f, 0.f};

        for (int kt = 0; kt < 8; kt++) {
            const int k0 = kt * 32;
            union { short8 v; unsigned short u[8]; } av;
            const int gr = row0 + ar;
            if (gr < NN) {
                const float* xp = x + (size_t)gr * KD + k0 + aq * 8;
                float4 f0 = *(const float4*)xp;
                float4 f1 = *(const float4*)(xp + 4);
                av.u[0] = f2bf(f0.x); av.u[1] = f2bf(f0.y);
                av.u[2] = f2bf(f0.z); av.u[3] = f2bf(f0.w);
                av.u[4] = f2bf(f1.x); av.u[5] = f2bf(f1.y);
                av.u[6] = f2bf(f1.z); av.u[7] = f2bf(f1.w);
            } else {
                av.v = (short8){0,0,0,0,0,0,0,0};
            }
            __syncthreads();   // protect As from previous phase/iter readers
            *(short8*)&As[ar][aq * 8] = av.v;
            const unsigned short* wp = Wt + (size_t)bn * KD + k0 + bh;
            *(short8*)&Bs[bn][bh]     = *(const short8*)wp;
            *(short8*)&Bs[bn][bh + 8] = *(const short8*)(wp + 8);
            __syncthreads();
            short8 af = *(const short8*)&As[m0 + lr][quad * 8];
#pragma unroll
            for (int nt = 0; nt < 8; nt++) {
                short8 bfr = *(const short8*)&Bs[nt * 16 + lr][quad * 8];
                acc[nt] = __builtin_amdgcn_mfma_f32_16x16x32_bf16(af, bfr, acc[nt], 0, 0, 0);
            }
        }
#pragma unroll
        for (int i = 0; i < 4; i++) {
            const int grow = row0 + m0 + quad * 4 + i;
            if (grow < NN) {
                unsigned short* hp = hb + (size_t)grow * CD + lr;
#pragma unroll
                for (int nt = 0; nt < 8; nt++)
                    hp[nt * 16] = f2bf(acc[nt][i]);
            }
        }
    } else {
        for (int e = (b - GEMM_BLOCKS) * 256 + tid; e < NE; e += HIST_BLOCKS * 256) {
            unsigned long long p = (1ull << 40)
                                 + (unsigned long long)(ew[e] * 4294967296.0f);
            unsigned long long old = atomicAdd(&packed[col[e]], p);
            rank[e] = (unsigned short)(old >> 40);
        }
    }
    grid.sync();

    // ---------------- phase 2a: per-block local scan
    int* sm = (int*)&As[0][0];   // 1 KB scratch
    if (b < NB) {
        const int g = b * 256 + tid;
        int v = (g < NN) ? (int)(packed[g] >> 40) : 0;
        sm[tid] = v;
        __syncthreads();
#pragma unroll
        for (int off = 1; off < 256; off <<= 1) {
            int u = (tid >= off) ? sm[tid - off] : 0;
            __syncthreads();
            sm[tid] += u;
            __syncthreads();
        }
        local[g] = sm[tid] - v;
        if (tid == 255) partials[b] = sm[tid];
    }
    grid.sync();

    // ---------------- phase 2b: apply block base; dinv = rsqrt(1+sum_ew)
    if (b < NB) {
        sm[tid] = (tid < b) ? partials[tid] : 0;   // b <= 195 < 256
        __syncthreads();
#pragma unroll
        for (int off = 128; off > 0; off >>= 1) {
            if (tid < off) sm[tid] += sm[tid + off];
            __syncthreads();
        }
        const int base = sm[0];
        const int g = b * 256 + tid;
        if (g < NN) {
            start[g] = local[g] + base;
            float degs = (float)(packed[g] & ((1ull << 40) - 1)) * (1.0f / 4294967296.0f);
            dinv[g] = rsqrtf(1.0f + degs);
        }
        if (g == 0) start[NN] = NE;
    }
    grid.sync();

    // ---------------- phase 3: meta[start[col]+rank] = {bf16 w | u16 row}
    for (int e = b * 256 + tid; e < NE; e += GRID * 256) {
        int c = col[e];
        int r = row[e];
        int pos = start[c] + rank[e];
        unsigned short wbf = f2bf(dinv[r] * ew[e]);
        meta[pos] = ((unsigned)wbf << 16) | (unsigned)r;
    }
    grid.sync();

    // ---------------- phase 4: pull aggregation, one wave per node, 8-way ILP
    const int lane = tid & 63;
    const int wv   = b * 4 + (tid >> 6);
    for (int n = wv; n < NN; n += GRID * 4) {
        const int s = __builtin_amdgcn_readfirstlane(start[n]);
        const int e = __builtin_amdgcn_readfirstlane(start[n + 1]);
        float A0[8], A1[8];
#pragma unroll
        for (int j = 0; j < 8; j++) { A0[j] = 0.f; A1[j] = 0.f; }
        int i = s;
        for (; i + 8 <= e; i += 8) {
            unsigned m[8], u[8];
#pragma unroll
            for (int j = 0; j < 8; j++) m[j] = meta[i + j];
#pragma unroll
            for (int j = 0; j < 8; j++)
                u[j] = *(const unsigned*)(hb + (size_t)(m[j] & 0xFFFFu) * CD + lane * 2);
#pragma unroll
            for (int j = 0; j < 8; j++) {
                float w = __uint_as_float(m[j] & 0xFFFF0000u);
                A0[j] = fmaf(w, bf2f_lo(u[j]), A0[j]);
                A1[j] = fmaf(w, bf2f_hi(u[j]), A1[j]);
            }
        }
        for (; i < e; i++) {
            unsigned m = meta[i];
            unsigned u = *(const unsigned*)(hb + (size_t)(m & 0xFFFFu) * CD + lane * 2);
            float w = __uint_as_float(m & 0xFFFF0000u);
            A0[0] = fmaf(w, bf2f_lo(u), A0[0]);
            A1[0] = fmaf(w, bf2f_hi(u), A1[0]);
        }
#pragma unroll
        for (int j = 1; j < 8; j++) { A0[0] += A0[j]; A1[0] += A1[j]; }

        const float dc = dinv[n];
        unsigned us = *(const unsigned*)(hb + (size_t)n * CD + lane * 2);
        const int ch = lane * 2;
        float o0 = dc * A0[0] + dc * dc * bf2f_lo(us) + bias[ch];
        float o1 = dc * A1[0] + dc * dc * bf2f_hi(us) + bias[ch + 1];
        o0 = o0 >= 0.f ? o0 : alpha[ch] * o0;
        o1 = o1 >= 0.f ? o1 : alpha[ch + 1] * o1;
        *(float2*)(out + (size_t)n * CD + ch) = make_float2(o0, o1);
    }
}

extern "C" void kernel_launch(void* const* d_in, const int* in_sizes, int n_in,
                              void* d_out, int out_size, void* d_ws, size_t ws_size,
                              hipStream_t stream) {
    const float* x     = (const float*)d_in[0];
    const int*   eidx  = (const int*)d_in[1];   // [2, NE]
    const float* ew    = (const float*)d_in[2];
    const float* Wm    = (const float*)d_in[3];
    const float* bias  = (const float*)d_in[4];
    const float* alpha = (const float*)d_in[5];
    const int* row = eidx;
    const int* col = eidx + NE;

    float* out = (float*)d_out;

    // workspace layout (bytes, 16B-aligned sections)
    char* ws = (char*)d_ws;
    unsigned long long* packed = (unsigned long long*)(ws);      // NN u64   [0, 400000)
    int*   start    = (int*)(ws + 400000);                       // NN+1 int
    int*   local    = (int*)(ws + 600016);                       // 50176 int
    int*   partials = (int*)(ws + 800720);                       // NB int
    float* dinv     = (float*)(ws + 801504);                     // NN f32
    unsigned short* rank = (unsigned short*)(ws + 1001504);      // NE u16 (1.6 MB)
    unsigned* meta  = (unsigned*)(ws + 2601504);                 // NE u32 (3.2 MB)
    unsigned short* Wt = (unsigned short*)(ws + 5801504);        // 128*256 bf16
    unsigned short* hb = (unsigned short*)(ws + 5867040);        // NN*128 bf16 (12.8 MB)

    void* args[] = {
        (void*)&x, (void*)&Wm, (void*)&col, (void*)&ew, (void*)&row,
        (void*)&bias, (void*)&alpha, (void*)&out,
        (void*)&packed, (void*)&start, (void*)&local, (void*)&partials,
        (void*)&dinv, (void*)&rank, (void*)&meta, (void*)&Wt, (void*)&hb
    };
    hipLaunchCooperativeKernel((const void*)mega, dim3(GRID), dim3(256),
                               args, 0, stream);
}

// Round 10
// 272.564 us; speedup vs baseline: 2.9891x; 2.9891x over previous
//
#include <hip/hip_runtime.h>
#include <hip/hip_cooperative_groups.h>

namespace cg = cooperative_groups;

#define NN 50000
#define NE 800000
#define KD 256
#define CD 128
#define NB 196            // scan blocks: 196*256 = 50176 >= NN
#define GEMM_BLOCKS 782   // (NN+63)/64
#define HIST_BLOCKS 3125  // (NE+255)/256
#define MIDG 256          // cooperative mid-kernel grid (1 block/CU, trivially co-resident)

typedef __attribute__((ext_vector_type(8))) short short8;
typedef __attribute__((ext_vector_type(4))) float floatx4;

__device__ inline unsigned short f2bf(float f) {
    unsigned u = __float_as_uint(f);
    unsigned r = (u + 0x7FFFu + ((u >> 16) & 1u)) >> 16;   // RNE
    return (unsigned short)r;
}
__device__ inline float bf2f_lo(unsigned u) { return __uint_as_float(u << 16); }
__device__ inline float bf2f_hi(unsigned u) { return __uint_as_float(u & 0xFFFF0000u); }

// ====== prep: blocks 0..31 transpose W (fp32[K][N] -> bf16[N][K]); rest zero packed
__global__ __launch_bounds__(256) void prep(const float* __restrict__ Wm,
                                            unsigned short* __restrict__ Wt,
                                            unsigned long long* __restrict__ packed) {
    if (blockIdx.x < 32) {
        __shared__ unsigned short t[32][33];
        const int bk = (blockIdx.x >> 2) * 32;
        const int bn = (blockIdx.x & 3) * 32;
        const int tx = threadIdx.x & 31;
        const int ty = threadIdx.x >> 5;
#pragma unroll
        for (int i = 0; i < 32; i += 8)
            t[ty + i][tx] = f2bf(Wm[(size_t)(bk + ty + i) * CD + bn + tx]);
        __syncthreads();
#pragma unroll
        for (int i = 0; i < 32; i += 8)
            Wt[(size_t)(bn + ty + i) * KD + bk + tx] = t[tx][ty + i];
    } else {
        int idx = (blockIdx.x - 32) * 256 + threadIdx.x;
        if (idx < NN) packed[idx] = 0;
    }
}

// ===== fused: GEMM tiles (blocks < GEMM_BLOCKS) + degree histogram (rest) =====
// count in [40:64), fixpoint sum(ew) in [0:40); returned old count = rank.
__global__ __launch_bounds__(256) void fused_gemm_hist(
        const float* __restrict__ x, const unsigned short* __restrict__ Wt,
        unsigned short* __restrict__ hb,
        const int* __restrict__ col, const float* __restrict__ ew,
        unsigned long long* __restrict__ packed, unsigned short* __restrict__ rank) {
    __shared__ unsigned short As[64][40];
    __shared__ unsigned short Bs[128][40];

    if (blockIdx.x >= GEMM_BLOCKS) {
        int e = (blockIdx.x - GEMM_BLOCKS) * 256 + threadIdx.x;
        if (e < NE) {
            unsigned long long p = (1ull << 40)
                                 + (unsigned long long)(ew[e] * 4294967296.0f);
            unsigned long long old = atomicAdd(&packed[col[e]], p);
            rank[e] = (unsigned short)(old >> 40);
        }
        return;
    }

    const int tid  = threadIdx.x;
    const int wave = tid >> 6;
    const int lane = tid & 63;
    const int row0 = blockIdx.x * 64;
    const int m0   = wave * 16;
    const int lr   = lane & 15;
    const int quad = lane >> 4;

    const int ar = tid >> 2;
    const int aq = tid & 3;
    const int bn = tid >> 1;
    const int bh = (tid & 1) * 16;

    floatx4 acc[8];
#pragma unroll
    for (int nt = 0; nt < 8; nt++) acc[nt] = (floatx4){0.f, 0.f, 0.f, 0.f};

    for (int kt = 0; kt < 8; kt++) {
        const int k0 = kt * 32;
        union { short8 v; unsigned short u[8]; } av;
        const int gr = row0 + ar;
        if (gr < NN) {
            const float* xp = x + (size_t)gr * KD + k0 + aq * 8;
            float4 f0 = *(const float4*)xp;
            float4 f1 = *(const float4*)(xp + 4);
            av.u[0] = f2bf(f0.x); av.u[1] = f2bf(f0.y);
            av.u[2] = f2bf(f0.z); av.u[3] = f2bf(f0.w);
            av.u[4] = f2bf(f1.x); av.u[5] = f2bf(f1.y);
            av.u[6] = f2bf(f1.z); av.u[7] = f2bf(f1.w);
        } else {
            av.v = (short8){0,0,0,0,0,0,0,0};
        }
        *(short8*)&As[ar][aq * 8] = av.v;
        const unsigned short* wp = Wt + (size_t)bn * KD + k0 + bh;
        *(short8*)&Bs[bn][bh]     = *(const short8*)wp;
        *(short8*)&Bs[bn][bh + 8] = *(const short8*)(wp + 8);
        __syncthreads();
        short8 af = *(const short8*)&As[m0 + lr][quad * 8];
#pragma unroll
        for (int nt = 0; nt < 8; nt++) {
            short8 bfr = *(const short8*)&Bs[nt * 16 + lr][quad * 8];
            acc[nt] = __builtin_amdgcn_mfma_f32_16x16x32_bf16(af, bfr, acc[nt], 0, 0, 0);
        }
        __syncthreads();
    }

#pragma unroll
    for (int i = 0; i < 4; i++) {
        const int grow = row0 + m0 + quad * 4 + i;
        if (grow < NN) {
            unsigned short* hp = hb + (size_t)grow * CD + lr;
#pragma unroll
            for (int nt = 0; nt < 8; nt++)
                hp[nt * 16] = f2bf(acc[nt][i]);
        }
    }
}

// ====== cooperative mid: scan(2 phases) + meta_write, register-light, no MFMA
__global__ __launch_bounds__(256) void mid(
        const unsigned long long* __restrict__ packed,
        int* __restrict__ local, int* __restrict__ partials,
        int* __restrict__ start, float* __restrict__ dinv,
        const int* __restrict__ row, const int* __restrict__ col,
        const float* __restrict__ ew, const unsigned short* __restrict__ rank,
        unsigned* __restrict__ meta) {
    cg::grid_group grid = cg::this_grid();
    __shared__ int sm[256];
    const int t = threadIdx.x;
    const int b = blockIdx.x;

    // ---- phase A: per-block local exclusive scan of counts
    if (b < NB) {
        const int g = b * 256 + t;
        int v = (g < NN) ? (int)(packed[g] >> 40) : 0;
        sm[t] = v;
        __syncthreads();
#pragma unroll
        for (int off = 1; off < 256; off <<= 1) {
            int u = (t >= off) ? sm[t - off] : 0;
            __syncthreads();
            sm[t] += u;
            __syncthreads();
        }
        local[g] = sm[t] - v;
        if (t == 255) partials[b] = sm[t];
    }
    grid.sync();

    // ---- phase B: block base via tree-reduce; emit start, dinv
    if (b < NB) {
        sm[t] = (t < b) ? partials[t] : 0;   // b <= 195 < 256
        __syncthreads();
#pragma unroll
        for (int off = 128; off > 0; off >>= 1) {
            if (t < off) sm[t] += sm[t + off];
            __syncthreads();
        }
        const int base = sm[0];
        const int g = b * 256 + t;
        if (g < NN) {
            start[g] = local[g] + base;
            float degs = (float)(packed[g] & ((1ull << 40) - 1)) * (1.0f / 4294967296.0f);
            dinv[g] = rsqrtf(1.0f + degs);
        }
        if (g == 0) start[NN] = NE;
    }
    grid.sync();

    // ---- phase C: meta[start[col]+rank] = {bf16 w | u16 row}, grid-stride
    for (int e = b * 256 + t; e < NE; e += MIDG * 256) {
        int c = col[e];
        int r = row[e];
        int pos = start[c] + rank[e];
        unsigned short wbf = f2bf(dinv[r] * ew[e]);
        meta[pos] = ((unsigned)wbf << 16) | (unsigned)r;
    }
}

// ---------- pull aggregation: one wave per node, bf16 h, 8-way ILP, fused epilogue
__global__ __launch_bounds__(256) void aggregate(const int* __restrict__ start,
                                                 const unsigned* __restrict__ meta,
                                                 const unsigned short* __restrict__ hb,
                                                 const float* __restrict__ dinv,
                                                 const float* __restrict__ bias,
                                                 const float* __restrict__ alpha,
                                                 float* __restrict__ out) {
    int n = blockIdx.x * 4 + (threadIdx.x >> 6);
    if (n >= NN) return;
    n = __builtin_amdgcn_readfirstlane(n);
    const int lane = threadIdx.x & 63;
    const int s = __builtin_amdgcn_readfirstlane(start[n]);
    const int e = __builtin_amdgcn_readfirstlane(start[n + 1]);

    float A0[8], A1[8];
#pragma unroll
    for (int j = 0; j < 8; j++) { A0[j] = 0.f; A1[j] = 0.f; }

    int i = s;
    for (; i + 8 <= e; i += 8) {
        unsigned m[8], u[8];
#pragma unroll
        for (int j = 0; j < 8; j++) m[j] = meta[i + j];
#pragma unroll
        for (int j = 0; j < 8; j++)
            u[j] = *(const unsigned*)(hb + (size_t)(m[j] & 0xFFFFu) * CD + lane * 2);
#pragma unroll
        for (int j = 0; j < 8; j++) {
            float w = __uint_as_float(m[j] & 0xFFFF0000u);
            A0[j] = fmaf(w, bf2f_lo(u[j]), A0[j]);
            A1[j] = fmaf(w, bf2f_hi(u[j]), A1[j]);
        }
    }
    for (; i < e; i++) {
        unsigned m = meta[i];
        unsigned u = *(const unsigned*)(hb + (size_t)(m & 0xFFFFu) * CD + lane * 2);
        float w = __uint_as_float(m & 0xFFFF0000u);
        A0[0] = fmaf(w, bf2f_lo(u), A0[0]);
        A1[0] = fmaf(w, bf2f_hi(u), A1[0]);
    }
#pragma unroll
    for (int j = 1; j < 8; j++) { A0[0] += A0[j]; A1[0] += A1[j]; }

    const float dc = dinv[n];
    unsigned us = *(const unsigned*)(hb + (size_t)n * CD + lane * 2);
    const int ch = lane * 2;
    float o0 = dc * A0[0] + dc * dc * bf2f_lo(us) + bias[ch];
    float o1 = dc * A1[0] + dc * dc * bf2f_hi(us) + bias[ch + 1];
    o0 = o0 >= 0.f ? o0 : alpha[ch] * o0;
    o1 = o1 >= 0.f ? o1 : alpha[ch + 1] * o1;
    *(float2*)(out + (size_t)n * CD + ch) = make_float2(o0, o1);
}

extern "C" void kernel_launch(void* const* d_in, const int* in_sizes, int n_in,
                              void* d_out, int out_size, void* d_ws, size_t ws_size,
                              hipStream_t stream) {
    const float* x     = (const float*)d_in[0];
    const int*   eidx  = (const int*)d_in[1];   // [2, NE]
    const float* ew    = (const float*)d_in[2];
    const float* Wm    = (const float*)d_in[3];
    const float* bias  = (const float*)d_in[4];
    const float* alpha = (const float*)d_in[5];
    const int* row = eidx;
    const int* col = eidx + NE;

    float* out = (float*)d_out;

    // workspace layout (bytes)
    char* ws = (char*)d_ws;
    unsigned long long* packed = (unsigned long long*)(ws);      // NN u64 (400000)
    int*   start    = (int*)(ws + 400000);                       // NN+1 int
    int*   local    = (int*)(ws + 600016);                       // 50176 int
    int*   partials = (int*)(ws + 800720);                       // NB int
    float* dinv     = (float*)(ws + 801504);                     // NN f32
    unsigned short* rank = (unsigned short*)(ws + 1001504);      // NE u16 (1.6 MB)
    unsigned* meta  = (unsigned*)(ws + 2601504);                 // NE u32 (3.2 MB)
    unsigned short* Wt = (unsigned short*)(ws + 5801504);        // 128*256 bf16
    unsigned short* hb = (unsigned short*)(ws + 5867040);        // NN*128 bf16 (12.8 MB)

    prep          <<<228, 256, 0, stream>>>(Wm, Wt, packed);
    fused_gemm_hist<<<GEMM_BLOCKS + HIST_BLOCKS, 256, 0, stream>>>(
                        x, Wt, hb, col, ew, packed, rank);

    void* margs[] = {
        (void*)&packed, (void*)&local, (void*)&partials, (void*)&start,
        (void*)&dinv, (void*)&row, (void*)&col, (void*)&ew,
        (void*)&rank, (void*)&meta
    };
    hipLaunchCooperativeKernel((const void*)mid, dim3(MIDG), dim3(256),
                               margs, 0, stream);

    aggregate     <<<(NN + 3) / 4, 256, 0, stream>>>(start, meta, hb, dinv, bias, alpha, out);
}